// Round 3
// baseline (926.552 us; speedup 1.0000x reference)
//
#include <hip/hip_runtime.h>

// Causal per-channel FIR via FFT (fft_size=16384) as packed 8192-pt complex
// FFTs. B=8, N=8192, D=512. Round 6: k2 rebuilt as parity-split pair of
// 4096-pt convs (even bins = FFT4096(z), odd = FFT4096(z*w^n)), one
// 256-thread block does both sequentially in 32KB LDS (ye held in regs,
// combine y = ye + conj(w^n)*yo). 4096 = 16x16x16: three fft16 levels,
// zero shuffles, 5 blocks/CU target via __launch_bounds__(256,5).
// k01/k3/tables unchanged from R5 (passing baseline).

typedef float v2f __attribute__((ext_vector_type(2)));

#define PQ_STRIDE 4097
constexpr double PI_D = 3.14159265358979323846;

// ---- static device tables (input-independent, filled by k_init) ----
__device__ v2f    g_twA[15][512];  // e^{-i pi * tid * (j+1) / 4096}   (8192-FFT, k01)
__device__ v2f    g_twB[15][32];   // e^{-i pi * m2 * (j+1) / 256}     (8192-FFT, k01)
__device__ v2f    g_w81[4096];     // (cos, sin)(pi k / 8192)
__device__ v2f    g_h[4096];       // ((1-s)/2, (1+s)/2) double-accurate
__device__ float4 g_u[4097];       // (c/(1-s), c/(1+s), (1+s)/(1-s), (1-s)/(1+s))
__device__ v2f    g_tA4[15][256];  // e^{-2pi i * t * (j+1) / 4096}    (4096-FFT, k2)
__device__ v2f    g_tB4[15][16];   // e^{-2pi i * n3 * (j+1) / 256}    (4096-FFT, k2)
__device__ v2f    g_wt4[256];      // e^{-2pi i * t / 8192}            (parity twist)

__device__ __forceinline__ v2f mkv2(float x, float y) { v2f r; r.x = x; r.y = y; return r; }
// a*b  (complex)
__device__ __forceinline__ v2f cmul(v2f a, v2f b)  { return mkv2(a.x, a.x) * b + mkv2(-a.y, a.y) * b.yx; }
// a*conj(b)
__device__ __forceinline__ v2f cmulc(v2f a, v2f b) { return mkv2(a.x, -a.x) * b + mkv2(a.y, a.y) * b.yx; }
// conj(a)*b
__device__ __forceinline__ v2f cmulcA(v2f a, v2f b){ return mkv2(a.x, a.x) * b + mkv2(a.y, -a.y) * b.yx; }

// FFT16 leaves output X[k] in v[SLOT(k)]
#define SLOT(k) ((((k) & 3) << 2) | ((k) >> 2))

// ---- LDS layouts for the 8192-pt machinery (k01 only), unchanged ----
__device__ __forceinline__ int addr1(int n2, int k1) {            // A[k1, n2]
    return (n2 << 4) | ((k1 + n2) & 15);
}
__device__ __forceinline__ int addr2(int r, int m2) {             // B[r=(k1*16+q1), m2]
    return (r << 5) | ((m2 + 2 * r) & 31);
}
__device__ __forceinline__ int addr3(int k) {                     // X[k], k natural bin
    int lo = (k + 2 * (k >> 4) + (k >> 8) + (k >> 12)) & 15;
    return (k & ~15) | lo;
}

// ---- LDS layouts for the 4096-pt machinery (k2), all < 4096 ----
// each 16-lane phase hits 16 distinct bank-pairs (rotated low digit)
__device__ __forceinline__ int addrA4(int t, int k1) {            // A[k1, t], t in [0,256)
    return (t << 4) | ((k1 + t) & 15);
}
__device__ __forceinline__ int addrB4(int r, int n3) {            // B[r=k1*16+k2, n3]
    return (r << 4) | ((n3 + r) & 15);
}
__device__ __forceinline__ int addrX4(int k) {                    // X[k], k = k1+16*k2+256*k3
    return (k & ~15) | ((k + (k >> 4) + 2 * (k >> 8)) & 15);
}

// radix-4 butterfly. SGN=-1 forward, +1 inverse.
template <int SGN>
__device__ __forceinline__ void fft4(v2f& a, v2f& b, v2f& c, v2f& d) {
    v2f A0 = a + c, A1 = a - c, A2 = b + d, A3 = b - d;
    v2f T = (SGN < 0) ? mkv2(A3.y, -A3.x) : mkv2(-A3.y, A3.x);
    a = A0 + A2; b = A1 + T; c = A0 - A2; d = A1 - T;
}

template <int SGN>
__device__ __forceinline__ void fft16_tail(v2f* v) {
    const float C1 = 0.9238795325112867f, S1 = 0.3826834323650898f, R2 = 0.7071067811865476f;
    v[5]  = cmul(v[5],  mkv2(C1, SGN < 0 ? -S1 : S1));
    v[6]  = cmul(v[6],  mkv2(R2, SGN < 0 ? -R2 : R2));
    v[7]  = cmul(v[7],  mkv2(S1, SGN < 0 ? -C1 : C1));
    v[9]  = cmul(v[9],  mkv2(R2, SGN < 0 ? -R2 : R2));
    v[10] = (SGN < 0) ? mkv2(v[10].y, -v[10].x) : mkv2(-v[10].y, v[10].x);
    v[11] = cmul(v[11], mkv2(-R2, SGN < 0 ? -R2 : R2));
    v[13] = cmul(v[13], mkv2(S1, SGN < 0 ? -C1 : C1));
    v[14] = cmul(v[14], mkv2(-R2, SGN < 0 ? -R2 : R2));
    v[15] = cmul(v[15], mkv2(-C1, SGN < 0 ? S1 : -S1));
    fft4<SGN>(v[0], v[1], v[2], v[3]);
    fft4<SGN>(v[4], v[5], v[6], v[7]);
    fft4<SGN>(v[8], v[9], v[10], v[11]);
    fft4<SGN>(v[12], v[13], v[14], v[15]);
}
template <int SGN>
__device__ __forceinline__ void fft16(v2f* v) {   // natural in, X[k] at SLOT(k)
    fft4<SGN>(v[0], v[4], v[8], v[12]);
    fft4<SGN>(v[1], v[5], v[9], v[13]);
    fft4<SGN>(v[2], v[6], v[10], v[14]);
    fft4<SGN>(v[3], v[7], v[11], v[15]);
    fft16_tail<SGN>(v);
}
template <int SGN>
__device__ __forceinline__ void fft16_half(v2f* v) {  // v[0..7] in, upper half = 0
    #pragma unroll
    for (int j = 0; j < 4; ++j) {
        v2f a = v[j], b = v[j + 4];
        v2f T = (SGN < 0) ? mkv2(b.y, -b.x) : mkv2(-b.y, b.x);
        v[j] = a + b; v[j + 4] = a + T;
        v[j + 8] = a - b; v[j + 12] = a - T;
    }
    fft16_tail<SGN>(v);
}

__device__ __forceinline__ v2f shflx1(v2f v) {
    return mkv2(__shfl_xor(v.x, 1), __shfl_xor(v.y, 1));
}

#define W32_TABLES \
    constexpr float WC[16] = {1.f, 0.98078528f, 0.92387953f, 0.83146961f, 0.70710678f, \
        0.55557023f, 0.38268343f, 0.19509032f, 0.f, -0.19509032f, -0.38268343f, \
        -0.55557023f, -0.70710678f, -0.83146961f, -0.92387953f, -0.98078528f}; \
    constexpr float WS[16] = {0.f, 0.19509032f, 0.38268343f, 0.55557023f, 0.70710678f, \
        0.83146961f, 0.92387953f, 0.98078528f, 1.f, 0.98078528f, 0.92387953f, \
        0.83146961f, 0.70710678f, 0.55557023f, 0.38268343f, 0.19509032f};

// ======== 8192-pt helpers (k01 spectrum path only) ========

__device__ __forceinline__ void fwd_L2_L3(v2f* sbuf, int tid) {
    {   // L2: 16-pt FFT over m1 for each (k1, m2), twiddle from g_twB
        int k1 = tid >> 5, m2 = tid & 31;
        v2f w[15];
        #pragma unroll
        for (int j = 0; j < 15; ++j) w[j] = g_twB[j][m2];
        v2f u[16];
        #pragma unroll
        for (int m1 = 0; m1 < 16; ++m1) u[m1] = sbuf[addr1(32 * m1 + m2, k1)];
        __syncthreads();
        fft16<-1>(u);
        #pragma unroll
        for (int k = 1; k < 16; ++k) u[SLOT(k)] = cmul(u[SLOT(k)], w[k - 1]);
        #pragma unroll
        for (int q1 = 0; q1 < 16; ++q1) sbuf[addr2(k1 * 16 + q1, m2)] = u[SLOT(q1)];
        __syncthreads();
    }
    {   // L3: 32-pt FFT over m2 for each (k1,q1): paired threads, shfl combine
        int k1 = tid >> 5, q1 = (tid >> 1) & 15, half = tid & 1;
        v2f e[16];
        #pragma unroll
        for (int j = 0; j < 16; ++j) e[j] = sbuf[addr2(k1 * 16 + q1, 2 * j + half)];
        __syncthreads();
        fft16<-1>(e);
        W32_TABLES
        #pragma unroll
        for (int q = 0; q < 16; ++q) {
            v2f mine = e[SLOT(q)];
            v2f othr = shflx1(mine);
            v2f Eq = half ? othr : mine;
            v2f Oq = half ? mine : othr;
            v2f WO = cmul(mkv2(WC[q], -WS[q]), Oq);
            v2f X = half ? Eq - WO : Eq + WO;
            int k = k1 + 16 * q1 + 256 * (q + 16 * half);
            sbuf[addr3(k)] = X;
        }
        __syncthreads();
    }
}

__device__ __forceinline__ void inv_L3_L2(v2f* sbuf, int tid) {
    {   // inv L3
        int k1 = tid >> 5, q1 = (tid >> 1) & 15, half = tid & 1;
        v2f t[16];
        #pragma unroll
        for (int q = 0; q < 16; ++q)
            t[q] = sbuf[addr3(k1 + 16 * q1 + 256 * (q + 16 * half))];
        __syncthreads();
        W32_TABLES
        #pragma unroll
        for (int q = 0; q < 16; ++q) {
            v2f othr = shflx1(t[q]);
            if (half) t[q] = cmul(mkv2(WC[q], WS[q]), othr - t[q]);
            else      t[q] = t[q] + othr;
        }
        fft16<1>(t);
        #pragma unroll
        for (int j = 0; j < 16; ++j) sbuf[addr2(k1 * 16 + q1, 2 * j + half)] = t[SLOT(j)];
        __syncthreads();
    }
    {   // inv L2: twiddle = conj(g_twB) applied to inputs (natural index)
        int k1 = tid >> 5, m2 = tid & 31;
        v2f w[15];
        #pragma unroll
        for (int j = 0; j < 15; ++j) w[j] = g_twB[j][m2];
        v2f u[16];
        #pragma unroll
        for (int q1 = 0; q1 < 16; ++q1) u[q1] = sbuf[addr2(k1 * 16 + q1, m2)];
        __syncthreads();
        #pragma unroll
        for (int k = 1; k < 16; ++k) u[k] = cmulc(u[k], w[k - 1]);
        fft16<1>(u);
        #pragma unroll
        for (int m1 = 0; m1 < 16; ++m1) sbuf[addr1(32 * m1 + m2, k1)] = u[SLOT(m1)];
        __syncthreads();
    }
}

__device__ __forceinline__ void inv_L1(const v2f* sbuf, int tid, v2f* v) {
    v2f w[15];
    #pragma unroll
    for (int j = 0; j < 15; ++j) w[j] = g_twA[j][tid];
    #pragma unroll
    for (int k1 = 0; k1 < 16; ++k1) v[k1] = sbuf[addr1(tid, k1)];
    #pragma unroll
    for (int k = 1; k < 16; ++k) v[k] = cmulc(v[k], w[k - 1]);
    fft16<1>(v);
}

// Linear interp of coeffs (512 -> 8192, half-pixel), a[0]=dc.
__device__ __forceinline__ float aval(const float* C, float dcv, int idx) {
    if (idx == 0) return dcv;
    int j = idx - 1;
    float src = ((float)j + 0.5f) * 0.0625f - 0.5f;
    src = fminf(fmaxf(src, 0.0f), 511.0f);
    int lo = (int)floorf(src);
    int hi = min(lo + 1, 511);
    float w = src - (float)lo;
    return C[lo] * (1.0f - w) + C[hi] * w;
}

// ---- fused packed-domain spectrum multiply (4096-layout addressing) ------
// Z'k = al*Zk + i*(R*conj(Zm));  Z'm = conj(Dt)*Zm + i*conj(R*Zk)
// with al = P+Q, R = u1*P - u2*Q, Dt = u3*P + u4*Q; korig = bin of the
// original 8192-pt spectrum (indexes PQ and g_u).
__device__ __forceinline__ void spec_single4(v2f* sbuf, const float4* PQd, int j, int korig) {
    float4 uu = g_u[korig];
    float4 pq = PQd[korig];
    v2f P = mkv2(pq.x, pq.y), Q = mkv2(pq.z, pq.w);
    v2f al = P + Q;
    v2f R  = P * uu.x - Q * uu.y;
    int a = addrX4(j);
    v2f Z = sbuf[a];
    v2f W = cmulc(R, Z);
    sbuf[a] = cmul(al, Z) + mkv2(-W.y, W.x);
}
__device__ __forceinline__ void spec_pair4(v2f* sbuf, const float4* PQd, int j, int jm, int korig) {
    float4 uu = g_u[korig];
    float4 pq = PQd[korig];
    v2f P = mkv2(pq.x, pq.y), Q = mkv2(pq.z, pq.w);
    int ak = addrX4(j), am = addrX4(jm);
    v2f Zk = sbuf[ak], Zm = sbuf[am];
    v2f al = P + Q;
    v2f R  = P * uu.x - Q * uu.y;
    v2f Dt = P * uu.z + Q * uu.w;
    v2f W = cmulc(R, Zm);            // R * conj(Zm)
    v2f V = cmul(R, Zk);             // R * Zk
    sbuf[ak] = cmul(al, Zk) + mkv2(-W.y, W.x);   // + i*W
    sbuf[am] = cmulcA(Dt, Zm) + V.yx;            // conj(Dt)*Zm + i*conj(V)
}

// ======== 4096-pt conv core (k2): fwd 16x16x16 -> spec(parity) -> inv ====
// In: v[n1] = time sample z4[n1*256 + tid] (natural). Out: y at v[SLOT(n1)],
// unnormalized by 4096 (PQ carries 1/8192 = the split's (1/4096)*(1/2)).
// LDS sbuf: 4096 v2f = 32KB, fully reused across phases.
template <int PARITY>
__device__ __forceinline__ void conv4096(v2f* sbuf, int tid, v2f* v, const float4* PQd) {
    int k1 = tid >> 4, lo = tid & 15;
    // L1: fft16 over n1, twiddle W4096^{tid*k1}
    fft16<-1>(v);
    {
        v2f w[15];
        #pragma unroll
        for (int j = 0; j < 15; ++j) w[j] = g_tA4[j][tid];
        #pragma unroll
        for (int k = 1; k < 16; ++k) v[SLOT(k)] = cmul(v[SLOT(k)], w[k - 1]);
    }
    #pragma unroll
    for (int q = 0; q < 16; ++q) sbuf[addrA4(tid, q)] = v[SLOT(q)];
    __syncthreads();
    // L2: thread (k1, n3=lo): fft16 over n2, twiddle W256^{n3*k2}
    {
        v2f u[16];
        #pragma unroll
        for (int n2 = 0; n2 < 16; ++n2) u[n2] = sbuf[addrA4(n2 * 16 + lo, k1)];
        __syncthreads();
        fft16<-1>(u);
        v2f w[15];
        #pragma unroll
        for (int j = 0; j < 15; ++j) w[j] = g_tB4[j][lo];
        #pragma unroll
        for (int k = 1; k < 16; ++k) u[SLOT(k)] = cmul(u[SLOT(k)], w[k - 1]);
        #pragma unroll
        for (int k2 = 0; k2 < 16; ++k2) sbuf[addrB4(k1 * 16 + k2, lo)] = u[SLOT(k2)];
        __syncthreads();
    }
    // L3: thread (k1, k2=lo): fft16 over n3 -> bins k = k1 + 16*k2 + 256*k3
    {
        v2f e[16];
        #pragma unroll
        for (int n3 = 0; n3 < 16; ++n3) e[n3] = sbuf[addrB4(k1 * 16 + lo, n3)];
        __syncthreads();
        fft16<-1>(e);
        #pragma unroll
        for (int k3 = 0; k3 < 16; ++k3) sbuf[addrX4(k1 + 16 * lo + 256 * k3)] = e[SLOT(k3)];
        __syncthreads();
    }
    // spec: even parity pairs (j, 4096-j), korig=2j (+ singles 0, 2048);
    //       odd parity pairs (j, 4095-j), korig=2j+1
    #pragma unroll
    for (int t = 0; t < 8; ++t) {
        int j = tid + (t << 8);
        if (PARITY == 0) {
            if (j == 0) { spec_single4(sbuf, PQd, 0, 0); spec_single4(sbuf, PQd, 2048, 4096); }
            else        spec_pair4(sbuf, PQd, j, 4096 - j, 2 * j);
        } else {
            spec_pair4(sbuf, PQd, j, 4095 - j, 2 * j + 1);
        }
    }
    __syncthreads();
    // inv L3
    {
        v2f t[16];
        #pragma unroll
        for (int k3 = 0; k3 < 16; ++k3) t[k3] = sbuf[addrX4(k1 + 16 * lo + 256 * k3)];
        __syncthreads();
        fft16<1>(t);
        #pragma unroll
        for (int n3 = 0; n3 < 16; ++n3) sbuf[addrB4(k1 * 16 + lo, n3)] = t[SLOT(n3)];
        __syncthreads();
    }
    // inv L2: conj twiddle on natural k2 index, then inverse fft16
    {
        v2f u[16];
        #pragma unroll
        for (int k2 = 0; k2 < 16; ++k2) u[k2] = sbuf[addrB4(k1 * 16 + k2, lo)];
        __syncthreads();
        v2f w[15];
        #pragma unroll
        for (int j = 0; j < 15; ++j) w[j] = g_tB4[j][lo];
        #pragma unroll
        for (int k = 1; k < 16; ++k) u[k] = cmulc(u[k], w[k - 1]);
        fft16<1>(u);
        #pragma unroll
        for (int n2 = 0; n2 < 16; ++n2) sbuf[addrA4(n2 * 16 + lo, k1)] = u[SLOT(n2)];
        __syncthreads();
    }
    // inv L1: conj twiddle on natural k1 index, inverse fft16 -> time
    {
        #pragma unroll
        for (int q = 0; q < 16; ++q) v[q] = sbuf[addrA4(tid, q)];
        v2f w[15];
        #pragma unroll
        for (int j = 0; j < 15; ++j) w[j] = g_tA4[j][tid];
        #pragma unroll
        for (int k = 1; k < 16; ++k) v[k] = cmulc(v[k], w[k - 1]);
        fft16<1>(v);
    }
}

// ---- table init (input-independent, double precision) --------------------
__global__ void k_init() {
    int t = blockIdx.x * 512 + threadIdx.x;
    if (t < 4096) {
        double th = (PI_D / 8192.0) * (double)t;
        double s = sin(th), c = cos(th);
        g_w81[t] = mkv2((float)c, (float)s);
        g_h[t]   = mkv2((float)(0.5 * (1.0 - s)), (float)(0.5 * (1.0 + s)));
    }
    if (t <= 4096) {
        if (t == 4096) {
            g_u[t] = make_float4(0.f, 0.f, 0.f, 0.f);
        } else {
            double th = (PI_D / 8192.0) * (double)t;
            double s = sin(th), c = cos(th);
            g_u[t] = make_float4((float)(c / (1.0 - s)), (float)(c / (1.0 + s)),
                                 (float)((1.0 + s) / (1.0 - s)), (float)((1.0 - s) / (1.0 + s)));
        }
    }
    if (t < 7680) {
        int j = t >> 9, tt = t & 511;
        double th = -(PI_D / 4096.0) * (double)(tt * (j + 1));
        g_twA[j][tt] = mkv2((float)cos(th), (float)sin(th));
    }
    if (t < 480) {
        int j = t >> 5, m2 = t & 31;
        double th = -(PI_D / 256.0) * (double)(m2 * (j + 1));
        g_twB[j][m2] = mkv2((float)cos(th), (float)sin(th));
    }
    if (t < 3840) {   // g_tA4: e^{-2pi i tt (j+1)/4096}
        int j = t >> 8, tt = t & 255;
        double th = -(2.0 * PI_D / 4096.0) * (double)(tt * (j + 1));
        g_tA4[j][tt] = mkv2((float)cos(th), (float)sin(th));
    }
    if (t < 240) {    // g_tB4: e^{-2pi i n3 (j+1)/256}
        int j = t >> 4, n3 = t & 15;
        double th = -(2.0 * PI_D / 256.0) * (double)(n3 * (j + 1));
        g_tB4[j][n3] = mkv2((float)cos(th), (float)sin(th));
    }
    if (t < 256) {    // g_wt4: e^{-2pi i t/8192}
        double th = -(2.0 * PI_D / 8192.0) * (double)t;
        g_wt4[t] = mkv2((float)cos(th), (float)sin(th));
    }
}

// Fused: blocks [0,512) build PQ tables; blocks [512, 512+8192) transpose/pack x.
__global__ __launch_bounds__(512, 4) void k01(const float* __restrict__ x,
                                              const float* __restrict__ coeffs,
                                              const float* __restrict__ dc,
                                              float4* __restrict__ PQ,
                                              v2f* __restrict__ zin) {
    __shared__ v2f sbuf[8192];
    int tid = threadIdx.x;
    if (blockIdx.x < 512) {
        int d = blockIdx.x;
        const float* C = coeffs + d * 512;
        float dcv = dc[d];
        // Z_A[k] = Ae + i*Ao*e^{+i pi k/M}  (packed-irfft spectrum), into LDS3
        #pragma unroll
        for (int tt = 0; tt < 16; ++tt) {
            int k = tid + (tt << 9);
            float ak = aval(C, dcv, k);
            float am = aval(C, dcv, 8192 - k);
            float Ae = 0.5f * (ak + am), Ao = 0.5f * (ak - am);
            float sn, cs;
            if (tt < 8) { v2f w = g_w81[k];        cs = w.x;  sn = w.y; }
            else        { v2f w = g_w81[k - 4096]; cs = -w.y; sn = w.x; }
            sbuf[addr3(k)] = mkv2(Ae - Ao * sn, Ao * cs);
        }
        __syncthreads();
        inv_L3_L2(sbuf, tid);
        v2f v[16];
        inv_L1(sbuf, tid, v);          // packed time, x8192 scale
        // causal Hilbert window + renormalize; reorder to natural n1
        v2f u[16];
        #pragma unroll
        for (int n1 = 0; n1 < 16; ++n1) {
            v2f z = v[SLOT(n1)];
            int n = (n1 << 9) + tid;
            float te = z.x * (1.0f / 8192.0f);
            float to = z.y * (1.0f / 8192.0f);
            int m0 = 2 * n;
            float he = (m0 == 0) ? te : ((m0 < 8192) ? 2.0f * te : ((m0 == 8192) ? te : 0.0f));
            float ho = (m0 + 1 < 8192) ? 2.0f * to : 0.0f;
            u[n1] = mkv2(he, ho);
        }
        // forward L1 (full): same-row rewrite of LDS1, no barrier needed before
        fft16<-1>(u);
        v2f wA[15];
        #pragma unroll
        for (int j = 0; j < 15; ++j) wA[j] = g_twA[j][tid];
        #pragma unroll
        for (int k = 1; k < 16; ++k) u[SLOT(k)] = cmul(u[SLOT(k)], wA[k - 1]);
        #pragma unroll
        for (int k1 = 0; k1 < 16; ++k1) sbuf[addr1(tid, k1)] = u[SLOT(k1)];
        __syncthreads();
        fwd_L2_L3(sbuf, tid);
        // unpack packed-real FFT -> (P,Q) table rows, bins k in [0,4096] ONLY
        float4* PQd = PQ + (size_t)d * PQ_STRIDE;
        const float scale = 1.0f / 8192.0f;
        #pragma unroll
        for (int tt = 0; tt < 8; ++tt) {
            int k = tid + (tt << 9);
            if (k == 0) {
                v2f Z0 = sbuf[addr3(0)];
                float S0 = (Z0.x + Z0.y) * scale;   // real
                float SM = (Z0.x - Z0.y) * scale;   // real
                PQd[0] = make_float4(0.5f * S0, 0.0f, 0.5f * SM, 0.0f);
                v2f Z4 = sbuf[addr3(4096)];
                float px = 0.5f * Z4.x * scale, py = 0.5f * Z4.y * scale;
                PQd[4096] = make_float4(px, py, px, py);
            } else {
                int km = 8192 - k;
                v2f Zk = sbuf[addr3(k)], Zm = sbuf[addr3(km)];
                v2f Xe = mkv2((Zk.x + Zm.x) * 0.5f, (Zk.y - Zm.y) * 0.5f);
                v2f dz = mkv2((Zk.x - Zm.x) * 0.5f, (Zk.y + Zm.y) * 0.5f);
                v2f Xo = mkv2(dz.y, -dz.x);
                v2f w = g_w81[k];                    // (cos, sin)(pi k/8192)
                v2f wXo = cmulc(Xo, w);              // Xo * (c, -s)
                v2f Sk  = (Xe + wXo) * scale;
                v2f SmC = (Xe - wXo) * scale;        // = conj(S_{M-k})
                v2f h = g_h[k];                      // ((1-s)/2, (1+s)/2) exact
                v2f Pk = Sk * h.x, Qk = SmC * h.y;
                PQd[k] = make_float4(Pk.x, Pk.y, Qk.x, Qk.y);
            }
        }
    } else {
        // transpose/pack: x(B,N,D) -> zin[(d*8+b)][n'] = x[b][2n'][d] + i x[b][2n'+1][d]
        int bid = blockIdx.x - 512;
        int nt = bid & 127, dt = (bid >> 7) & 7, bb = bid >> 10;
        float* tile = (float*)sbuf;    // [64 n][65] floats
        const float4* x4 = (const float4*)(x + ((size_t)bb * 8192 + (size_t)nt * 64) * 512 + dt * 64);
        int lane4 = tid & 15, row = tid >> 4;   // row 0..31
        #pragma unroll
        for (int r = 0; r < 2; ++r) {
            int rr = row + 32 * r;
            float4 vv = x4[(size_t)rr * 128 + lane4];
            float* dst = &tile[rr * 65 + lane4 * 4];
            dst[0] = vv.x; dst[1] = vv.y; dst[2] = vv.z; dst[3] = vv.w;
        }
        __syncthreads();
        int tx4 = tid & 15, dl = tid >> 4;      // dl 0..31
        #pragma unroll
        for (int r = 0; r < 2; ++r) {
            int dloc = dl + 32 * r;
            int d = dt * 64 + dloc;
            int npb = nt * 32 + 2 * tx4;
            float4 w;
            w.x = tile[(4 * tx4 + 0) * 65 + dloc];
            w.y = tile[(4 * tx4 + 1) * 65 + dloc];
            w.z = tile[(4 * tx4 + 2) * 65 + dloc];
            w.w = tile[(4 * tx4 + 3) * 65 + dloc];
            *(float4*)&zin[((size_t)(d * 8 + bb)) * 4096 + npb] = w;
        }
    }
}

// K2: parity-split conv. One 256-thread block per (d,b): even 4096-conv
// (ye held in regs), odd 4096-conv (input pre-twisted by w8192^n), combine
// y[n] = ye[n] + conj(w8192^n)*yo[n], write first-half time samples.
__global__ __launch_bounds__(256, 5) void k2_conv(const v2f* __restrict__ zin,
                                                  const float4* __restrict__ PQ,
                                                  v2f* __restrict__ yout) {
    __shared__ v2f sbuf[4096];
    int wg = blockIdx.x, tid = threadIdx.x;
    // XCD-aware swizzle: all 8 b-blocks of one d land on the same XCD.
    int xcd = wg & 7, idx = wg >> 3;
    int d = (xcd << 6) | (idx >> 3), b = idx & 7;
    int io = d * 8 + b;
    const v2f* zi = zin + (size_t)io * 4096;
    const float4* PQd = PQ + (size_t)d * PQ_STRIDE;
    W32_TABLES     // c32[n1] = e^{-2pi i n1/32} = (WC[n1], -WS[n1])

    // ---- even parity: Ze = FFT4096(z) ----
    v2f v[16];
    #pragma unroll
    for (int n1 = 0; n1 < 16; ++n1) v[n1] = zi[(n1 << 8) + tid];
    conv4096<0>(sbuf, tid, v, PQd);
    v2f ye[16];
    #pragma unroll
    for (int i = 0; i < 16; ++i) ye[i] = v[i];
    __syncthreads();   // even inv-L1 reads done before odd L1 stores

    // ---- odd parity: Zo = FFT4096(z * w8192^n), w8192^n = c32[n1]*wt[tid] ----
    v2f wt = g_wt4[tid];
    #pragma unroll
    for (int n1 = 0; n1 < 16; ++n1) {
        v2f t16 = cmul(wt, mkv2(WC[n1], -WS[n1]));
        v[n1] = cmul(zi[(n1 << 8) + tid], t16);
    }
    conv4096<1>(sbuf, tid, v, PQd);

    // ---- combine + write: y = ye + conj(w8192^n)*yo (scale already in PQ) ----
    v2f* yo = yout + (size_t)io * 4096;
    #pragma unroll
    for (int n1 = 0; n1 < 16; ++n1) {
        v2f t16 = cmul(wt, mkv2(WC[n1], -WS[n1]));
        yo[(n1 << 8) + tid] = ye[SLOT(n1)] + cmulc(v[SLOT(n1)], t16);
    }
}

// K3: yout[(d*8+b)][n'] -> out[b][2n'+e][d], float4 on both global sides.
__global__ __launch_bounds__(512) void k3_unpack(const float2* __restrict__ yout,
                                                 float* __restrict__ out) {
    __shared__ float2 tile[64 * 33];   // [d-local 64][np-local 32] pad 33
    int bid = blockIdx.x;
    int nt = bid & 127, dt = (bid >> 7) & 7, bb = bid >> 10;
    int tid = threadIdx.x;
    const float4* y4 = (const float4*)yout;
    int tx4 = tid & 15, dl = tid >> 4;      // dl 0..31
    #pragma unroll
    for (int r = 0; r < 2; ++r) {
        int dloc = dl + 32 * r;
        int d = dt * 64 + dloc;
        float4 vv = y4[(size_t)(d * 8 + bb) * 2048 + nt * 16 + tx4];
        tile[dloc * 33 + 2 * tx4]     = make_float2(vv.x, vv.y);
        tile[dloc * 33 + 2 * tx4 + 1] = make_float2(vv.z, vv.w);
    }
    __syncthreads();
    const float* tf = (const float*)tile;
    int lane4 = tid & 15, nl = tid >> 4;    // nl 0..31
    #pragma unroll
    for (int r = 0; r < 2; ++r) {
        int nloc = nl + 32 * r;             // 0..63
        int npl = nloc >> 1, e = nloc & 1;
        float4 w;
        w.x = tf[((4 * lane4 + 0) * 33 + npl) * 2 + e];
        w.y = tf[((4 * lane4 + 1) * 33 + npl) * 2 + e];
        w.z = tf[((4 * lane4 + 2) * 33 + npl) * 2 + e];
        w.w = tf[((4 * lane4 + 3) * 33 + npl) * 2 + e];
        int n = nt * 64 + nloc;
        *(float4*)&out[((size_t)bb * 8192 + n) * 512 + dt * 64 + lane4 * 4] = w;
    }
}

extern "C" void kernel_launch(void* const* d_in, const int* in_sizes, int n_in,
                              void* d_out, int out_size, void* d_ws, size_t ws_size,
                              hipStream_t stream) {
    const float* x      = (const float*)d_in[0];   // (8, 8192, 512)
    const float* coeffs = (const float*)d_in[1];   // (512, 512)
    const float* dc     = (const float*)d_in[2];   // (512, 1)
    float* out = (float*)d_out;                    // (8, 8192, 512)

    float4* PQ  = (float4*)d_ws;                                   // 512*4097 f4
    v2f*    zbuf = (v2f*)((char*)d_ws + (size_t)512 * PQ_STRIDE * sizeof(float4)); // 4096*4096 c

    k_init<<<15, 512, 0, stream>>>();
    k01<<<512 + 8192, 512, 0, stream>>>(x, coeffs, dc, PQ, zbuf);
    k2_conv<<<4096, 256, 0, stream>>>(zbuf, PQ, zbuf);   // in-place per-wg
    k3_unpack<<<8192, 512, 0, stream>>>((const float2*)zbuf, out);
}

// Round 4
// 488.249 us; speedup vs baseline: 1.8977x; 1.8977x over previous
//
#include <hip/hip_runtime.h>

// Causal per-channel FIR via FFT (fft_size=16384) as packed 8192-pt complex
// FFTs. B=8, N=8192, D=512. Round 7: k2 = parity-split pair of 4096-pt convs
// run CONCURRENTLY by two wave-groups of one 512-thread block (waves 0-3 even
// parity, waves 4-7 odd; parity is wave-uniform, unified code path => all
// barriers convergent). Each half owns a 32KB LDS buffer; combine goes
// through LDS (no ye-in-regs => no spills; R6's failure was the 102-VGPR cap
// vs 128-reg live set, spilling 1.9GB to scratch). conv4096 math verbatim
// from R6 (hardware-verified correct). k01/k3/tables unchanged from R5.

typedef float v2f __attribute__((ext_vector_type(2)));

#define PQ_STRIDE 4097
constexpr double PI_D = 3.14159265358979323846;

// ---- static device tables (input-independent, filled by k_init) ----
__device__ v2f    g_twA[15][512];  // e^{-i pi * tid * (j+1) / 4096}   (8192-FFT, k01)
__device__ v2f    g_twB[15][32];   // e^{-i pi * m2 * (j+1) / 256}     (8192-FFT, k01)
__device__ v2f    g_w81[4096];     // (cos, sin)(pi k / 8192)
__device__ v2f    g_h[4096];       // ((1-s)/2, (1+s)/2) double-accurate
__device__ float4 g_u[4097];       // (c/(1-s), c/(1+s), (1+s)/(1-s), (1-s)/(1+s))
__device__ v2f    g_tA4[15][256];  // e^{-2pi i * t * (j+1) / 4096}    (4096-FFT, k2)
__device__ v2f    g_tB4[15][16];   // e^{-2pi i * n3 * (j+1) / 256}    (4096-FFT, k2)
__device__ v2f    g_wt4[256];      // e^{-2pi i * t / 8192}            (parity twist)

__device__ __forceinline__ v2f mkv2(float x, float y) { v2f r; r.x = x; r.y = y; return r; }
// a*b  (complex)
__device__ __forceinline__ v2f cmul(v2f a, v2f b)  { return mkv2(a.x, a.x) * b + mkv2(-a.y, a.y) * b.yx; }
// a*conj(b)
__device__ __forceinline__ v2f cmulc(v2f a, v2f b) { return mkv2(a.x, -a.x) * b + mkv2(a.y, a.y) * b.yx; }
// conj(a)*b
__device__ __forceinline__ v2f cmulcA(v2f a, v2f b){ return mkv2(a.x, a.x) * b + mkv2(a.y, -a.y) * b.yx; }

// FFT16 leaves output X[k] in v[SLOT(k)]
#define SLOT(k) ((((k) & 3) << 2) | ((k) >> 2))

// ---- LDS layouts for the 8192-pt machinery (k01 only), unchanged ----
__device__ __forceinline__ int addr1(int n2, int k1) {            // A[k1, n2]
    return (n2 << 4) | ((k1 + n2) & 15);
}
__device__ __forceinline__ int addr2(int r, int m2) {             // B[r=(k1*16+q1), m2]
    return (r << 5) | ((m2 + 2 * r) & 31);
}
__device__ __forceinline__ int addr3(int k) {                     // X[k], k natural bin
    int lo = (k + 2 * (k >> 4) + (k >> 8) + (k >> 12)) & 15;
    return (k & ~15) | lo;
}

// ---- LDS layouts for the 4096-pt machinery (k2), all < 4096 ----
__device__ __forceinline__ int addrA4(int t, int k1) {            // A[k1, t], t in [0,256)
    return (t << 4) | ((k1 + t) & 15);
}
__device__ __forceinline__ int addrB4(int r, int n3) {            // B[r=k1*16+k2, n3]
    return (r << 4) | ((n3 + r) & 15);
}
__device__ __forceinline__ int addrX4(int k) {                    // X[k], k = k1+16*k2+256*k3
    return (k & ~15) | ((k + (k >> 4) + 2 * (k >> 8)) & 15);
}

// radix-4 butterfly. SGN=-1 forward, +1 inverse.
template <int SGN>
__device__ __forceinline__ void fft4(v2f& a, v2f& b, v2f& c, v2f& d) {
    v2f A0 = a + c, A1 = a - c, A2 = b + d, A3 = b - d;
    v2f T = (SGN < 0) ? mkv2(A3.y, -A3.x) : mkv2(-A3.y, A3.x);
    a = A0 + A2; b = A1 + T; c = A0 - A2; d = A1 - T;
}

template <int SGN>
__device__ __forceinline__ void fft16_tail(v2f* v) {
    const float C1 = 0.9238795325112867f, S1 = 0.3826834323650898f, R2 = 0.7071067811865476f;
    v[5]  = cmul(v[5],  mkv2(C1, SGN < 0 ? -S1 : S1));
    v[6]  = cmul(v[6],  mkv2(R2, SGN < 0 ? -R2 : R2));
    v[7]  = cmul(v[7],  mkv2(S1, SGN < 0 ? -C1 : C1));
    v[9]  = cmul(v[9],  mkv2(R2, SGN < 0 ? -R2 : R2));
    v[10] = (SGN < 0) ? mkv2(v[10].y, -v[10].x) : mkv2(-v[10].y, v[10].x);
    v[11] = cmul(v[11], mkv2(-R2, SGN < 0 ? -R2 : R2));
    v[13] = cmul(v[13], mkv2(S1, SGN < 0 ? -C1 : C1));
    v[14] = cmul(v[14], mkv2(-R2, SGN < 0 ? -R2 : R2));
    v[15] = cmul(v[15], mkv2(-C1, SGN < 0 ? S1 : -S1));
    fft4<SGN>(v[0], v[1], v[2], v[3]);
    fft4<SGN>(v[4], v[5], v[6], v[7]);
    fft4<SGN>(v[8], v[9], v[10], v[11]);
    fft4<SGN>(v[12], v[13], v[14], v[15]);
}
template <int SGN>
__device__ __forceinline__ void fft16(v2f* v) {   // natural in, X[k] at SLOT(k)
    fft4<SGN>(v[0], v[4], v[8], v[12]);
    fft4<SGN>(v[1], v[5], v[9], v[13]);
    fft4<SGN>(v[2], v[6], v[10], v[14]);
    fft4<SGN>(v[3], v[7], v[11], v[15]);
    fft16_tail<SGN>(v);
}
template <int SGN>
__device__ __forceinline__ void fft16_half(v2f* v) {  // v[0..7] in, upper half = 0
    #pragma unroll
    for (int j = 0; j < 4; ++j) {
        v2f a = v[j], b = v[j + 4];
        v2f T = (SGN < 0) ? mkv2(b.y, -b.x) : mkv2(-b.y, b.x);
        v[j] = a + b; v[j + 4] = a + T;
        v[j + 8] = a - b; v[j + 12] = a - T;
    }
    fft16_tail<SGN>(v);
}

__device__ __forceinline__ v2f shflx1(v2f v) {
    return mkv2(__shfl_xor(v.x, 1), __shfl_xor(v.y, 1));
}

#define W32_TABLES \
    constexpr float WC[16] = {1.f, 0.98078528f, 0.92387953f, 0.83146961f, 0.70710678f, \
        0.55557023f, 0.38268343f, 0.19509032f, 0.f, -0.19509032f, -0.38268343f, \
        -0.55557023f, -0.70710678f, -0.83146961f, -0.92387953f, -0.98078528f}; \
    constexpr float WS[16] = {0.f, 0.19509032f, 0.38268343f, 0.55557023f, 0.70710678f, \
        0.83146961f, 0.92387953f, 0.98078528f, 1.f, 0.98078528f, 0.92387953f, \
        0.83146961f, 0.70710678f, 0.55557023f, 0.38268343f, 0.19509032f};

// ======== 8192-pt helpers (k01 spectrum path only) ========

__device__ __forceinline__ void fwd_L2_L3(v2f* sbuf, int tid) {
    {   // L2: 16-pt FFT over m1 for each (k1, m2), twiddle from g_twB
        int k1 = tid >> 5, m2 = tid & 31;
        v2f w[15];
        #pragma unroll
        for (int j = 0; j < 15; ++j) w[j] = g_twB[j][m2];
        v2f u[16];
        #pragma unroll
        for (int m1 = 0; m1 < 16; ++m1) u[m1] = sbuf[addr1(32 * m1 + m2, k1)];
        __syncthreads();
        fft16<-1>(u);
        #pragma unroll
        for (int k = 1; k < 16; ++k) u[SLOT(k)] = cmul(u[SLOT(k)], w[k - 1]);
        #pragma unroll
        for (int q1 = 0; q1 < 16; ++q1) sbuf[addr2(k1 * 16 + q1, m2)] = u[SLOT(q1)];
        __syncthreads();
    }
    {   // L3: 32-pt FFT over m2 for each (k1,q1): paired threads, shfl combine
        int k1 = tid >> 5, q1 = (tid >> 1) & 15, half = tid & 1;
        v2f e[16];
        #pragma unroll
        for (int j = 0; j < 16; ++j) e[j] = sbuf[addr2(k1 * 16 + q1, 2 * j + half)];
        __syncthreads();
        fft16<-1>(e);
        W32_TABLES
        #pragma unroll
        for (int q = 0; q < 16; ++q) {
            v2f mine = e[SLOT(q)];
            v2f othr = shflx1(mine);
            v2f Eq = half ? othr : mine;
            v2f Oq = half ? mine : othr;
            v2f WO = cmul(mkv2(WC[q], -WS[q]), Oq);
            v2f X = half ? Eq - WO : Eq + WO;
            int k = k1 + 16 * q1 + 256 * (q + 16 * half);
            sbuf[addr3(k)] = X;
        }
        __syncthreads();
    }
}

__device__ __forceinline__ void inv_L3_L2(v2f* sbuf, int tid) {
    {   // inv L3
        int k1 = tid >> 5, q1 = (tid >> 1) & 15, half = tid & 1;
        v2f t[16];
        #pragma unroll
        for (int q = 0; q < 16; ++q)
            t[q] = sbuf[addr3(k1 + 16 * q1 + 256 * (q + 16 * half))];
        __syncthreads();
        W32_TABLES
        #pragma unroll
        for (int q = 0; q < 16; ++q) {
            v2f othr = shflx1(t[q]);
            if (half) t[q] = cmul(mkv2(WC[q], WS[q]), othr - t[q]);
            else      t[q] = t[q] + othr;
        }
        fft16<1>(t);
        #pragma unroll
        for (int j = 0; j < 16; ++j) sbuf[addr2(k1 * 16 + q1, 2 * j + half)] = t[SLOT(j)];
        __syncthreads();
    }
    {   // inv L2: twiddle = conj(g_twB) applied to inputs (natural index)
        int k1 = tid >> 5, m2 = tid & 31;
        v2f w[15];
        #pragma unroll
        for (int j = 0; j < 15; ++j) w[j] = g_twB[j][m2];
        v2f u[16];
        #pragma unroll
        for (int q1 = 0; q1 < 16; ++q1) u[q1] = sbuf[addr2(k1 * 16 + q1, m2)];
        __syncthreads();
        #pragma unroll
        for (int k = 1; k < 16; ++k) u[k] = cmulc(u[k], w[k - 1]);
        fft16<1>(u);
        #pragma unroll
        for (int m1 = 0; m1 < 16; ++m1) sbuf[addr1(32 * m1 + m2, k1)] = u[SLOT(m1)];
        __syncthreads();
    }
}

__device__ __forceinline__ void inv_L1(const v2f* sbuf, int tid, v2f* v) {
    v2f w[15];
    #pragma unroll
    for (int j = 0; j < 15; ++j) w[j] = g_twA[j][tid];
    #pragma unroll
    for (int k1 = 0; k1 < 16; ++k1) v[k1] = sbuf[addr1(tid, k1)];
    #pragma unroll
    for (int k = 1; k < 16; ++k) v[k] = cmulc(v[k], w[k - 1]);
    fft16<1>(v);
}

// Linear interp of coeffs (512 -> 8192, half-pixel), a[0]=dc.
__device__ __forceinline__ float aval(const float* C, float dcv, int idx) {
    if (idx == 0) return dcv;
    int j = idx - 1;
    float src = ((float)j + 0.5f) * 0.0625f - 0.5f;
    src = fminf(fmaxf(src, 0.0f), 511.0f);
    int lo = (int)floorf(src);
    int hi = min(lo + 1, 511);
    float w = src - (float)lo;
    return C[lo] * (1.0f - w) + C[hi] * w;
}

// ---- fused packed-domain spectrum multiply (4096-layout addressing) ------
// Z'k = al*Zk + i*(R*conj(Zm));  Z'm = conj(Dt)*Zm + i*conj(R*Zk)
__device__ __forceinline__ void spec_single4(v2f* sbuf, const float4* PQd, int j, int korig) {
    float4 uu = g_u[korig];
    float4 pq = PQd[korig];
    v2f P = mkv2(pq.x, pq.y), Q = mkv2(pq.z, pq.w);
    v2f al = P + Q;
    v2f R  = P * uu.x - Q * uu.y;
    int a = addrX4(j);
    v2f Z = sbuf[a];
    v2f W = cmulc(R, Z);
    sbuf[a] = cmul(al, Z) + mkv2(-W.y, W.x);
}
__device__ __forceinline__ void spec_pair4(v2f* sbuf, const float4* PQd, int j, int jm, int korig) {
    float4 uu = g_u[korig];
    float4 pq = PQd[korig];
    v2f P = mkv2(pq.x, pq.y), Q = mkv2(pq.z, pq.w);
    int ak = addrX4(j), am = addrX4(jm);
    v2f Zk = sbuf[ak], Zm = sbuf[am];
    v2f al = P + Q;
    v2f R  = P * uu.x - Q * uu.y;
    v2f Dt = P * uu.z + Q * uu.w;
    v2f W = cmulc(R, Zm);            // R * conj(Zm)
    v2f V = cmul(R, Zk);             // R * Zk
    sbuf[ak] = cmul(al, Zk) + mkv2(-W.y, W.x);   // + i*W
    sbuf[am] = cmulcA(Dt, Zm) + V.yx;            // conj(Dt)*Zm + i*conj(V)
}

// ======== 4096-pt conv core (k2) — verified math (R6), runtime parity ====
// In: v[n1] = time sample z4[n1*256 + t]. Out: y at v[SLOT(n1)], x4096 scale
// folded into PQ. par is wave-uniform => unified barrier path.
__device__ __forceinline__ void conv4096(v2f* sbuf, int t, int par, v2f* v, const float4* PQd) {
    int k1 = t >> 4, lo = t & 15;
    // L1: fft16 over n1, twiddle W4096^{t*k1}
    fft16<-1>(v);
    {
        v2f w[15];
        #pragma unroll
        for (int j = 0; j < 15; ++j) w[j] = g_tA4[j][t];
        #pragma unroll
        for (int k = 1; k < 16; ++k) v[SLOT(k)] = cmul(v[SLOT(k)], w[k - 1]);
    }
    #pragma unroll
    for (int q = 0; q < 16; ++q) sbuf[addrA4(t, q)] = v[SLOT(q)];
    __syncthreads();
    // L2: thread (k1, n3=lo): fft16 over n2, twiddle W256^{n3*k2}
    {
        v2f u[16];
        #pragma unroll
        for (int n2 = 0; n2 < 16; ++n2) u[n2] = sbuf[addrA4(n2 * 16 + lo, k1)];
        __syncthreads();
        fft16<-1>(u);
        v2f w[15];
        #pragma unroll
        for (int j = 0; j < 15; ++j) w[j] = g_tB4[j][lo];
        #pragma unroll
        for (int k = 1; k < 16; ++k) u[SLOT(k)] = cmul(u[SLOT(k)], w[k - 1]);
        #pragma unroll
        for (int k2 = 0; k2 < 16; ++k2) sbuf[addrB4(k1 * 16 + k2, lo)] = u[SLOT(k2)];
        __syncthreads();
    }
    // L3: thread (k1, k2=lo): fft16 over n3 -> bins k = k1 + 16*k2 + 256*k3
    {
        v2f e[16];
        #pragma unroll
        for (int n3 = 0; n3 < 16; ++n3) e[n3] = sbuf[addrB4(k1 * 16 + lo, n3)];
        __syncthreads();
        fft16<-1>(e);
        #pragma unroll
        for (int k3 = 0; k3 < 16; ++k3) sbuf[addrX4(k1 + 16 * lo + 256 * k3)] = e[SLOT(k3)];
        __syncthreads();
    }
    // spec: even parity pairs (j, 4096-j), korig=2j (+ singles 0, 2048);
    //       odd parity pairs (j, 4095-j), korig=2j+1
    #pragma unroll
    for (int s = 0; s < 8; ++s) {
        int j = t + (s << 8);
        if (par == 0) {
            if (j == 0) { spec_single4(sbuf, PQd, 0, 0); spec_single4(sbuf, PQd, 2048, 4096); }
            else        spec_pair4(sbuf, PQd, j, 4096 - j, 2 * j);
        } else {
            spec_pair4(sbuf, PQd, j, 4095 - j, 2 * j + 1);
        }
    }
    __syncthreads();
    // inv L3
    {
        v2f tt[16];
        #pragma unroll
        for (int k3 = 0; k3 < 16; ++k3) tt[k3] = sbuf[addrX4(k1 + 16 * lo + 256 * k3)];
        __syncthreads();
        fft16<1>(tt);
        #pragma unroll
        for (int n3 = 0; n3 < 16; ++n3) sbuf[addrB4(k1 * 16 + lo, n3)] = tt[SLOT(n3)];
        __syncthreads();
    }
    // inv L2: conj twiddle on natural k2 index, then inverse fft16
    {
        v2f u[16];
        #pragma unroll
        for (int k2 = 0; k2 < 16; ++k2) u[k2] = sbuf[addrB4(k1 * 16 + k2, lo)];
        __syncthreads();
        v2f w[15];
        #pragma unroll
        for (int j = 0; j < 15; ++j) w[j] = g_tB4[j][lo];
        #pragma unroll
        for (int k = 1; k < 16; ++k) u[k] = cmulc(u[k], w[k - 1]);
        fft16<1>(u);
        #pragma unroll
        for (int n2 = 0; n2 < 16; ++n2) sbuf[addrA4(n2 * 16 + lo, k1)] = u[SLOT(n2)];
        __syncthreads();
    }
    // inv L1: conj twiddle on natural k1 index, inverse fft16 -> time
    {
        #pragma unroll
        for (int q = 0; q < 16; ++q) v[q] = sbuf[addrA4(t, q)];
        v2f w[15];
        #pragma unroll
        for (int j = 0; j < 15; ++j) w[j] = g_tA4[j][t];
        #pragma unroll
        for (int k = 1; k < 16; ++k) v[k] = cmulc(v[k], w[k - 1]);
        fft16<1>(v);
    }
}

// ---- table init (input-independent, double precision) --------------------
__global__ void k_init() {
    int t = blockIdx.x * 512 + threadIdx.x;
    if (t < 4096) {
        double th = (PI_D / 8192.0) * (double)t;
        double s = sin(th), c = cos(th);
        g_w81[t] = mkv2((float)c, (float)s);
        g_h[t]   = mkv2((float)(0.5 * (1.0 - s)), (float)(0.5 * (1.0 + s)));
    }
    if (t <= 4096) {
        if (t == 4096) {
            g_u[t] = make_float4(0.f, 0.f, 0.f, 0.f);
        } else {
            double th = (PI_D / 8192.0) * (double)t;
            double s = sin(th), c = cos(th);
            g_u[t] = make_float4((float)(c / (1.0 - s)), (float)(c / (1.0 + s)),
                                 (float)((1.0 + s) / (1.0 - s)), (float)((1.0 - s) / (1.0 + s)));
        }
    }
    if (t < 7680) {
        int j = t >> 9, tt = t & 511;
        double th = -(PI_D / 4096.0) * (double)(tt * (j + 1));
        g_twA[j][tt] = mkv2((float)cos(th), (float)sin(th));
    }
    if (t < 480) {
        int j = t >> 5, m2 = t & 31;
        double th = -(PI_D / 256.0) * (double)(m2 * (j + 1));
        g_twB[j][m2] = mkv2((float)cos(th), (float)sin(th));
    }
    if (t < 3840) {   // g_tA4: e^{-2pi i tt (j+1)/4096}
        int j = t >> 8, tt = t & 255;
        double th = -(2.0 * PI_D / 4096.0) * (double)(tt * (j + 1));
        g_tA4[j][tt] = mkv2((float)cos(th), (float)sin(th));
    }
    if (t < 240) {    // g_tB4: e^{-2pi i n3 (j+1)/256}
        int j = t >> 4, n3 = t & 15;
        double th = -(2.0 * PI_D / 256.0) * (double)(n3 * (j + 1));
        g_tB4[j][n3] = mkv2((float)cos(th), (float)sin(th));
    }
    if (t < 256) {    // g_wt4: e^{-2pi i t/8192}
        double th = -(2.0 * PI_D / 8192.0) * (double)t;
        g_wt4[t] = mkv2((float)cos(th), (float)sin(th));
    }
}

// Fused: blocks [0,512) build PQ tables; blocks [512, 512+8192) transpose/pack x.
__global__ __launch_bounds__(512, 4) void k01(const float* __restrict__ x,
                                              const float* __restrict__ coeffs,
                                              const float* __restrict__ dc,
                                              float4* __restrict__ PQ,
                                              v2f* __restrict__ zin) {
    __shared__ v2f sbuf[8192];
    int tid = threadIdx.x;
    if (blockIdx.x < 512) {
        int d = blockIdx.x;
        const float* C = coeffs + d * 512;
        float dcv = dc[d];
        // Z_A[k] = Ae + i*Ao*e^{+i pi k/M}  (packed-irfft spectrum), into LDS3
        #pragma unroll
        for (int tt = 0; tt < 16; ++tt) {
            int k = tid + (tt << 9);
            float ak = aval(C, dcv, k);
            float am = aval(C, dcv, 8192 - k);
            float Ae = 0.5f * (ak + am), Ao = 0.5f * (ak - am);
            float sn, cs;
            if (tt < 8) { v2f w = g_w81[k];        cs = w.x;  sn = w.y; }
            else        { v2f w = g_w81[k - 4096]; cs = -w.y; sn = w.x; }
            sbuf[addr3(k)] = mkv2(Ae - Ao * sn, Ao * cs);
        }
        __syncthreads();
        inv_L3_L2(sbuf, tid);
        v2f v[16];
        inv_L1(sbuf, tid, v);          // packed time, x8192 scale
        // causal Hilbert window + renormalize; reorder to natural n1
        v2f u[16];
        #pragma unroll
        for (int n1 = 0; n1 < 16; ++n1) {
            v2f z = v[SLOT(n1)];
            int n = (n1 << 9) + tid;
            float te = z.x * (1.0f / 8192.0f);
            float to = z.y * (1.0f / 8192.0f);
            int m0 = 2 * n;
            float he = (m0 == 0) ? te : ((m0 < 8192) ? 2.0f * te : ((m0 == 8192) ? te : 0.0f));
            float ho = (m0 + 1 < 8192) ? 2.0f * to : 0.0f;
            u[n1] = mkv2(he, ho);
        }
        // forward L1 (full): same-row rewrite of LDS1, no barrier needed before
        fft16<-1>(u);
        v2f wA[15];
        #pragma unroll
        for (int j = 0; j < 15; ++j) wA[j] = g_twA[j][tid];
        #pragma unroll
        for (int k = 1; k < 16; ++k) u[SLOT(k)] = cmul(u[SLOT(k)], wA[k - 1]);
        #pragma unroll
        for (int k1 = 0; k1 < 16; ++k1) sbuf[addr1(tid, k1)] = u[SLOT(k1)];
        __syncthreads();
        fwd_L2_L3(sbuf, tid);
        // unpack packed-real FFT -> (P,Q) table rows, bins k in [0,4096] ONLY
        float4* PQd = PQ + (size_t)d * PQ_STRIDE;
        const float scale = 1.0f / 8192.0f;
        #pragma unroll
        for (int tt = 0; tt < 8; ++tt) {
            int k = tid + (tt << 9);
            if (k == 0) {
                v2f Z0 = sbuf[addr3(0)];
                float S0 = (Z0.x + Z0.y) * scale;   // real
                float SM = (Z0.x - Z0.y) * scale;   // real
                PQd[0] = make_float4(0.5f * S0, 0.0f, 0.5f * SM, 0.0f);
                v2f Z4 = sbuf[addr3(4096)];
                float px = 0.5f * Z4.x * scale, py = 0.5f * Z4.y * scale;
                PQd[4096] = make_float4(px, py, px, py);
            } else {
                int km = 8192 - k;
                v2f Zk = sbuf[addr3(k)], Zm = sbuf[addr3(km)];
                v2f Xe = mkv2((Zk.x + Zm.x) * 0.5f, (Zk.y - Zm.y) * 0.5f);
                v2f dz = mkv2((Zk.x - Zm.x) * 0.5f, (Zk.y + Zm.y) * 0.5f);
                v2f Xo = mkv2(dz.y, -dz.x);
                v2f w = g_w81[k];                    // (cos, sin)(pi k/8192)
                v2f wXo = cmulc(Xo, w);              // Xo * (c, -s)
                v2f Sk  = (Xe + wXo) * scale;
                v2f SmC = (Xe - wXo) * scale;        // = conj(S_{M-k})
                v2f h = g_h[k];                      // ((1-s)/2, (1+s)/2) exact
                v2f Pk = Sk * h.x, Qk = SmC * h.y;
                PQd[k] = make_float4(Pk.x, Pk.y, Qk.x, Qk.y);
            }
        }
    } else {
        // transpose/pack: x(B,N,D) -> zin[(d*8+b)][n'] = x[b][2n'][d] + i x[b][2n'+1][d]
        int bid = blockIdx.x - 512;
        int nt = bid & 127, dt = (bid >> 7) & 7, bb = bid >> 10;
        float* tile = (float*)sbuf;    // [64 n][65] floats
        const float4* x4 = (const float4*)(x + ((size_t)bb * 8192 + (size_t)nt * 64) * 512 + dt * 64);
        int lane4 = tid & 15, row = tid >> 4;   // row 0..31
        #pragma unroll
        for (int r = 0; r < 2; ++r) {
            int rr = row + 32 * r;
            float4 vv = x4[(size_t)rr * 128 + lane4];
            float* dst = &tile[rr * 65 + lane4 * 4];
            dst[0] = vv.x; dst[1] = vv.y; dst[2] = vv.z; dst[3] = vv.w;
        }
        __syncthreads();
        int tx4 = tid & 15, dl = tid >> 4;      // dl 0..31
        #pragma unroll
        for (int r = 0; r < 2; ++r) {
            int dloc = dl + 32 * r;
            int d = dt * 64 + dloc;
            int npb = nt * 32 + 2 * tx4;
            float4 w;
            w.x = tile[(4 * tx4 + 0) * 65 + dloc];
            w.y = tile[(4 * tx4 + 1) * 65 + dloc];
            w.z = tile[(4 * tx4 + 2) * 65 + dloc];
            w.w = tile[(4 * tx4 + 3) * 65 + dloc];
            *(float4*)&zin[((size_t)(d * 8 + bb)) * 4096 + npb] = w;
        }
    }
}

// K2: parity-split conv, two concurrent wave-groups. Waves 0-3: even parity
// in sbuf[0..4096); waves 4-7: odd parity (input pre-twisted by w8192^n) in
// sbuf[4096..8192). Combine via LDS: y[n] = ye[n] + conj(w8192^n)*yo[n].
__global__ __launch_bounds__(512, 4) void k2_conv(const v2f* __restrict__ zin,
                                                  const float4* __restrict__ PQ,
                                                  v2f* __restrict__ yout) {
    __shared__ __align__(16) v2f sbuf[8192];
    int wg = blockIdx.x, tid = threadIdx.x;
    // XCD-aware swizzle: all 8 b-blocks of one d land on the same XCD.
    int xcd = wg & 7, idx = wg >> 3;
    int d = (xcd << 6) | (idx >> 3), b = idx & 7;
    int io = d * 8 + b;
    const v2f* zi = zin + (size_t)io * 4096;
    const float4* PQd = PQ + (size_t)d * PQ_STRIDE;
    int par = tid >> 8;            // wave-uniform: waves 0-3 even, 4-7 odd
    int t = tid & 255;
    v2f* sb = sbuf + (par << 12);
    W32_TABLES                     // e^{-2pi i n1/32} = (WC[n1], -WS[n1])
    v2f wt = g_wt4[t];

    v2f v[16];
    #pragma unroll
    for (int n1 = 0; n1 < 16; ++n1) v[n1] = zi[(n1 << 8) + t];
    if (par) {                     // odd parity: pre-twist z[n] *= w8192^n
        #pragma unroll
        for (int n1 = 0; n1 < 16; ++n1)
            v[n1] = cmul(v[n1], cmul(wt, mkv2(WC[n1], -WS[n1])));
    }
    conv4096(sb, t, par, v, PQd);
    __syncthreads();               // inv-L1 loads done before linear overwrite
    // exchange: even writes ye, odd writes conj(w8192^n)*yo, both linear
    #pragma unroll
    for (int n1 = 0; n1 < 16; ++n1) {
        v2f val = v[SLOT(n1)];
        if (par) val = cmulc(val, cmul(wt, mkv2(WC[n1], -WS[n1])));
        sb[(n1 << 8) + t] = val;
    }
    __syncthreads();
    // combine + store: all 512 threads, float4 (2 complex) per iteration
    v2f* yo = yout + (size_t)io * 4096;
    const float4* se = (const float4*)sbuf;          // [2048] = even half
    const float4* so = (const float4*)(sbuf + 4096); // odd half
    #pragma unroll
    for (int s = 0; s < 4; ++s) {
        int p = tid + (s << 9);    // float4 index in [0,2048)
        float4 e = se[p], o = so[p];
        float4 r = make_float4(e.x + o.x, e.y + o.y, e.z + o.z, e.w + o.w);
        *(float4*)&yo[2 * p] = r;
    }
}

// K3: yout[(d*8+b)][n'] -> out[b][2n'+e][d], float4 on both global sides.
__global__ __launch_bounds__(512) void k3_unpack(const float2* __restrict__ yout,
                                                 float* __restrict__ out) {
    __shared__ float2 tile[64 * 33];   // [d-local 64][np-local 32] pad 33
    int bid = blockIdx.x;
    int nt = bid & 127, dt = (bid >> 7) & 7, bb = bid >> 10;
    int tid = threadIdx.x;
    const float4* y4 = (const float4*)yout;
    int tx4 = tid & 15, dl = tid >> 4;      // dl 0..31
    #pragma unroll
    for (int r = 0; r < 2; ++r) {
        int dloc = dl + 32 * r;
        int d = dt * 64 + dloc;
        float4 vv = y4[(size_t)(d * 8 + bb) * 2048 + nt * 16 + tx4];
        tile[dloc * 33 + 2 * tx4]     = make_float2(vv.x, vv.y);
        tile[dloc * 33 + 2 * tx4 + 1] = make_float2(vv.z, vv.w);
    }
    __syncthreads();
    const float* tf = (const float*)tile;
    int lane4 = tid & 15, nl = tid >> 4;    // nl 0..31
    #pragma unroll
    for (int r = 0; r < 2; ++r) {
        int nloc = nl + 32 * r;             // 0..63
        int npl = nloc >> 1, e = nloc & 1;
        float4 w;
        w.x = tf[((4 * lane4 + 0) * 33 + npl) * 2 + e];
        w.y = tf[((4 * lane4 + 1) * 33 + npl) * 2 + e];
        w.z = tf[((4 * lane4 + 2) * 33 + npl) * 2 + e];
        w.w = tf[((4 * lane4 + 3) * 33 + npl) * 2 + e];
        int n = nt * 64 + nloc;
        *(float4*)&out[((size_t)bb * 8192 + n) * 512 + dt * 64 + lane4 * 4] = w;
    }
}

extern "C" void kernel_launch(void* const* d_in, const int* in_sizes, int n_in,
                              void* d_out, int out_size, void* d_ws, size_t ws_size,
                              hipStream_t stream) {
    const float* x      = (const float*)d_in[0];   // (8, 8192, 512)
    const float* coeffs = (const float*)d_in[1];   // (512, 512)
    const float* dc     = (const float*)d_in[2];   // (512, 1)
    float* out = (float*)d_out;                    // (8, 8192, 512)

    float4* PQ  = (float4*)d_ws;                                   // 512*4097 f4
    v2f*    zbuf = (v2f*)((char*)d_ws + (size_t)512 * PQ_STRIDE * sizeof(float4)); // 4096*4096 c

    k_init<<<15, 512, 0, stream>>>();
    k01<<<512 + 8192, 512, 0, stream>>>(x, coeffs, dc, PQ, zbuf);
    k2_conv<<<4096, 512, 0, stream>>>(zbuf, PQ, zbuf);   // in-place per-wg
    k3_unpack<<<8192, 512, 0, stream>>>((const float2*)zbuf, out);
}